// Round 12
// baseline (11368.325 us; speedup 1.0000x reference)
//
#include <hip/hip_runtime.h>
#include <stdint.h>

typedef unsigned short ushort_t;
typedef _Float16 f16_t;
typedef __attribute__((ext_vector_type(2))) _Float16 half2;
typedef __attribute__((ext_vector_type(8))) _Float16 half8;
typedef __attribute__((ext_vector_type(4))) float f32x4;

#define T_SEQ 4096
#define IN_SZ 512
#define H1 1024
#define H2 2048
#define G1 (4*H1)   // 4096
#define G2 (4*H2)   // 8192
#define OUT_SZ 512
#define L1OUT 1024

// f16 comm sentinel = 0x7C7C (f16 NaN pattern). h = o*tanh(c) in (-1,1) can never
// produce it (proven R1/R2/R11). Poison byte 0x7C.
#define SENT_H 0x7C7Cu

__device__ __forceinline__ float f16_val(ushort_t v) {
    union { ushort_t u; _Float16 h; } x; x.u = v; return (float)x.h;
}
__device__ __forceinline__ ushort_t f16_bits(float f) {
    union { _Float16 h; ushort_t u; } x; x.h = (_Float16)f; return x.u;
}
__device__ __forceinline__ half2 u2h(uint32_t w) {
    union { uint32_t u; half2 h; } x; x.u = w; return x.h;
}
// fast gate math
__device__ __forceinline__ float fsig(float x) {
    return __builtin_amdgcn_rcpf(1.0f + __expf(-x));
}
__device__ __forceinline__ float ftanh(float x) {
    return 1.0f - 2.0f * __builtin_amdgcn_rcpf(__expf(2.0f * x) + 1.0f);
}

// 2 MACs: acc += w·h for one packed f16 pair
__device__ __forceinline__ void dot2(float& acc, uint32_t w, uint32_t h) {
#if defined(__has_builtin) && __has_builtin(__builtin_amdgcn_fdot2)
    acc = __builtin_amdgcn_fdot2(u2h(w), u2h(h), acc, false);
#else
    half2 a = u2h(w), b = u2h(h);
    acc = fmaf((float)a.x, (float)b.x, acc);
    acc = fmaf((float)a.y, (float)b.y, acc);
#endif
}
#define DOT4(ACC, W, Hv) do { dot2(ACC, (W).x, (Hv).x); dot2(ACC, (W).y, (Hv).y); \
                              dot2(ACC, (W).z, (Hv).z); dot2(ACC, (W).w, (Hv).w); } while (0)

__device__ __forceinline__ uint64_t ald64(const uint64_t* p) {
    return __hip_atomic_load(p, __ATOMIC_RELAXED, __HIP_MEMORY_SCOPE_AGENT);
}
__device__ __forceinline__ int bad16x4(uint64_t q) {
    return (int)(((uint32_t)(q & 0xFFFFu)         == SENT_H) |
                 ((uint32_t)((q >> 16) & 0xFFFFu) == SENT_H) |
                 ((uint32_t)((q >> 32) & 0xFFFFu) == SENT_H) |
                 ((uint32_t)((q >> 48) & 0xFFFFu) == SENT_H));
}
__device__ __forceinline__ void ast16(ushort_t* p, ushort_t v) {
    __hip_atomic_store(p, v, __ATOMIC_RELAXED, __HIP_MEMORY_SCOPE_AGENT);
}

// ---------------- DPP reductions (VALU pipe; R10-proven +3.2ms win) ----------------
template<int CTRL>
__device__ __forceinline__ float dpp_add(float x) {
    union { float f; int i; } s, t;
    s.f = x;
    t.i = __builtin_amdgcn_update_dpp(0, s.i, CTRL, 0xF, 0xF, true);
    return x + t.f;
}
// sum of all 64 lanes -> valid on lane 63
__device__ __forceinline__ float red64(float x) {
    x = dpp_add<0x111>(x);   // row_shr:1
    x = dpp_add<0x112>(x);   // row_shr:2
    x = dpp_add<0x114>(x);   // row_shr:4
    x = dpp_add<0x118>(x);   // row_shr:8
    x = dpp_add<0x142>(x);   // row_bcast15
    x = dpp_add<0x143>(x);   // row_bcast31 -> lane63 = total
    return x;
}
// sum of each 32-lane half -> valid on lane 31 (lower) and lane 63 (upper)
__device__ __forceinline__ float red32(float x) {
    x = dpp_add<0x111>(x);
    x = dpp_add<0x112>(x);
    x = dpp_add<0x114>(x);
    x = dpp_add<0x118>(x);
    x = dpp_add<0x142>(x);
    return x;
}
__device__ __forceinline__ float bcast_lane63(float x) {
    union { float f; int i; } s;
    s.f = x;
    s.i = __builtin_amdgcn_readlane(s.i, 63);
    return s.f;
}

// ---------------- f32 -> f16 conversion ----------------
__global__ __launch_bounds__(256) void cvt_f16_kernel(const float* __restrict__ in,
                                                      f16_t* __restrict__ out, int n) {
    int i = blockIdx.x * 256 + threadIdx.x;
    int stride = gridDim.x * 256;
    for (; i < n; i += stride) out[i] = (f16_t)in[i];
}

// ---------------- f16 MFMA GEMM: C[M,N] = A[M,K] * B[N,K]^T + bias_a + bias_b, f16 out ----------
__global__ __launch_bounds__(256) void gemm_bt_kernel(const f16_t* __restrict__ A,
                                                      const f16_t* __restrict__ B,
                                                      f16_t* __restrict__ Cb,
                                                      const float* __restrict__ bias_a,
                                                      const float* __restrict__ bias_b,
                                                      int M, int N, int K) {
    int tid  = threadIdx.x;
    int wave = tid >> 6;
    int lane = tid & 63;
    int l15  = lane & 15;
    int quad = lane >> 4;
    int m0 = blockIdx.y * 64 + wave * 16;
    int n0 = blockIdx.x * 64;

    const f16_t* pa = A + (size_t)(m0 + l15) * K + quad * 8;
    f32x4 acc[4];
    #pragma unroll
    for (int i = 0; i < 4; ++i) acc[i] = (f32x4){0.f, 0.f, 0.f, 0.f};

    for (int kc = 0; kc < K; kc += 32) {
        half8 a = *(const half8*)(pa + kc);
        #pragma unroll
        for (int nf = 0; nf < 4; ++nf) {
            const f16_t* pb = B + (size_t)(n0 + nf * 16 + l15) * K + quad * 8 + kc;
            half8 b = *(const half8*)pb;
            acc[nf] = __builtin_amdgcn_mfma_f32_16x16x32_f16(a, b, acc[nf], 0, 0, 0);
        }
    }

    int rbase = quad * 4;
    #pragma unroll
    for (int nf = 0; nf < 4; ++nf) {
        int n = n0 + nf * 16 + l15;
        float bb = bias_a[n] + bias_b[n];
        #pragma unroll
        for (int r = 0; r < 4; ++r) {
            int m = m0 + rbase + r;
            Cb[(size_t)m * N + n] = (f16_t)(acc[nf][r] + bb);
        }
    }
}

// ---------------- Fused 2-layer LSTM recurrence, split-phase pipeline ----------------
// R11 champion (10.93ms: R4 schedule + DPP reductions + f16 comm) with ONE change:
// h1 poll becomes WAVE-DIRECT. Each lane polls exactly its dot slice of comm1[s-1]
// (4 u64 = words 4ln..4ln+3 and 256+4ln..+3 = hA/hB) straight into registers ->
// h1 LDS staging, its read-back, and BARRIER A are all deleted (1 barrier/step).
// Safety (audited): pre2->phaseC pb handoff is intra-wave (wave wv's pre2 rows are
// exactly its units 2wv,2wv+1); h2b double-buffer is safe with one barrier (B'(s+2)
// overwriting slot s&1 happens only after barrier-B(s+1), which implies all C(s)
// done); intra-block h1 publishes precede barrier-B(s) which precedes any poll of
// comm1[s]; cross-block visibility handled by the spin as before. Cost: 4x comm1
// read amplification (each wave reads the full row), served by local L2 after first
// touch. R1's failure mode (f32 + unpaced drift) is absent: f16 + barrier-paced.
// 256 blocks x 256 threads (1 block/CU). Block b owns h1 units [4b,4b+4), h2 units
// [8b,8b+8). Iteration s: [wave-direct poll h1[s-1]] B(h1[s], publish f16)
// pre2 B'(poll h2[s-2], stage) barrier C(h2[s-1], publish f16).
__global__ __launch_bounds__(256, 1) void fused_lstm_kernel(
        const f16_t* __restrict__ pre1,       // f16 [T, 4096]
        const ushort_t* __restrict__ whh1h,   // f16 bits [4096, 1024]
        const ushort_t* __restrict__ wih2h,   // f16 bits [8192, 1024]
        const ushort_t* __restrict__ whh2h,   // f16 bits [8192, 2048]
        const float* __restrict__ bih2,
        const float* __restrict__ bhh2,
        ushort_t* __restrict__ comm1,         // f16 [T, 1024], pre-poisoned 0x7C
        ushort_t* __restrict__ comm2,         // f16 [T, 2048], pre-poisoned 0x7C
        int T) {
    extern __shared__ char smem[];
    uint32_t* whh1_w = (uint32_t*)smem;             // [16][512]  f16-pair words (32KB)
    uint32_t* wih2_w = whh1_w + 16 * 512;           // [32][512]  (64KB)
    uint32_t* whh2_w = wih2_w + 32 * 512;           // [8][1024]  gate0 (32KB)
    uint32_t* h2b    = whh2_w + 8 * 1024;           // [2][1024]  packed h2 (8KB)

    int tid = threadIdx.x;
    int blk = blockIdx.x;
    int u1  = tid >> 6;          // h1 unit (0..3), 64 lanes
    int ln1 = tid & 63;
    int u2l = tid >> 5;          // h2 unit (0..7), 32 lanes
    int ln2 = tid & 31;
    int wv  = tid >> 6;          // wave id

    // ---- stage resident weights into LDS (f16 bytes, same layout as the global rows) ----
    #pragma unroll
    for (int i = 0; i < 8; ++i) {            // whh1: 16 rows x 128 uint4
        int idx = tid + i * 256, r = idx >> 7, ch = idx & 127;
        size_t R = (size_t)(r & 3) * H1 + blk * 4 + (r >> 2);
        *(uint4*)&whh1_w[r * 512 + ch * 4] = *(const uint4*)(whh1h + R * H1 + ch * 8);
    }
    #pragma unroll
    for (int i = 0; i < 16; ++i) {           // wih2: 32 rows x 128 uint4
        int idx = tid + i * 256, r = idx >> 7, ch = idx & 127;
        size_t R = (size_t)(r & 3) * H2 + blk * 8 + (r >> 2);
        *(uint4*)&wih2_w[r * 512 + ch * 4] = *(const uint4*)(wih2h + R * H1 + ch * 8);
    }
    #pragma unroll
    for (int i = 0; i < 8; ++i) {            // whh2 gate0: 8 rows x 256 uint4
        int idx = tid + i * 256, r = idx >> 8, ch = idx & 255;
        size_t R = (size_t)(blk * 8 + r);
        *(uint4*)&whh2_w[r * 1024 + ch * 4] = *(const uint4*)(whh2h + R * H2 + ch * 8);
    }

    // whh2 gates 1..3 (compiler schedules these at point of use in C; R4-verified ~free)
    uint4 wreg[24];
    #pragma unroll
    for (int g = 1; g < 4; ++g) {
        size_t R = (size_t)g * H2 + blk * 8 + u2l;
        #pragma unroll
        for (int j = 0; j < 8; ++j)
            wreg[(g - 1) * 8 + j] = *(const uint4*)(whh2h + R * H2 + ln2 * 8 + j * 256);
    }

    float b2g[4];
    {
        int U = blk * 8 + u2l;
        #pragma unroll
        for (int g = 0; g < 4; ++g) b2g[g] = bih2[g * H2 + U] + bhh2[g * H2 + U];
    }

    float pc[4] = {0.f, 0.f, 0.f, 0.f};
    if (ln1 == 63) {
        #pragma unroll
        for (int g = 0; g < 4; ++g)
            pc[g] = f16_val(((const ushort_t*)pre1)[(size_t)0 * G1 + g * H1 + blk * 4 + u1]);
    }

    float c1 = 0.0f;   // ln1==63
    float c2 = 0.0f;   // ln2==31

    __syncthreads();   // weights staged

    for (int s = 0; s <= T; ++s) {
        // ---- prefetch pre1[s+1] ----
        float pn[4] = {0.f, 0.f, 0.f, 0.f};
        if (ln1 == 63) {
            int row = (s + 1 < T) ? s + 1 : T - 1;
            #pragma unroll
            for (int g = 0; g < 4; ++g)
                pn[g] = f16_val(((const ushort_t*)pre1)[(size_t)row * G1 + g * H1 + blk * 4 + u1]);
        }

        // ---- wave-direct poll of h1[s-1]: each lane loads ITS dot slice (4 u64) ----
        uint4 hA, hB;
        if (s >= 1) {
            const uint64_t* s1 = (const uint64_t*)(comm1 + (size_t)(s - 1) * H1);
            uint64_t qa0, qa1, qb0, qb1;
            for (;;) {
                qa0 = ald64(&s1[2 * ln1]);
                qa1 = ald64(&s1[2 * ln1 + 1]);
                qb0 = ald64(&s1[128 + 2 * ln1]);
                qb1 = ald64(&s1[128 + 2 * ln1 + 1]);
                if (!(bad16x4(qa0) | bad16x4(qa1) | bad16x4(qb0) | bad16x4(qb1))) break;
                __builtin_amdgcn_s_sleep(1);
            }
            union { uint64_t q[2]; uint4 v; } ux;
            ux.q[0] = qa0; ux.q[1] = qa1; hA = ux.v;   // words 4ln..4ln+3
            ux.q[0] = qb0; ux.q[1] = qb1; hB = ux.v;   // words 256+4ln..+3
        }

        // ---- Phase B: h1[s] ----
        if (s < T) {
            float a0 = 0.f, a1 = 0.f, a2 = 0.f, a3 = 0.f;
            if (s >= 1) {
                uint4 w;
                w = *(const uint4*)&whh1_w[(u1 * 4 + 0) * 512 + ln1 * 4];       DOT4(a0, w, hA);
                w = *(const uint4*)&whh1_w[(u1 * 4 + 0) * 512 + ln1 * 4 + 256]; DOT4(a0, w, hB);
                w = *(const uint4*)&whh1_w[(u1 * 4 + 1) * 512 + ln1 * 4];       DOT4(a1, w, hA);
                w = *(const uint4*)&whh1_w[(u1 * 4 + 1) * 512 + ln1 * 4 + 256]; DOT4(a1, w, hB);
                w = *(const uint4*)&whh1_w[(u1 * 4 + 2) * 512 + ln1 * 4];       DOT4(a2, w, hA);
                w = *(const uint4*)&whh1_w[(u1 * 4 + 2) * 512 + ln1 * 4 + 256]; DOT4(a2, w, hB);
                w = *(const uint4*)&whh1_w[(u1 * 4 + 3) * 512 + ln1 * 4];       DOT4(a3, w, hA);
                w = *(const uint4*)&whh1_w[(u1 * 4 + 3) * 512 + ln1 * 4 + 256]; DOT4(a3, w, hB);
            }
            a0 = red64(a0); a1 = red64(a1); a2 = red64(a2); a3 = red64(a3);
            if (ln1 == 63) {
                float iv = fsig(pc[0] + a0);
                float fv = fsig(pc[1] + a1);
                float gv = ftanh(pc[2] + a2);
                float ov = fsig(pc[3] + a3);
                c1 = fv * c1 + iv * gv;
                float h = ov * ftanh(c1);
                ast16(&comm1[(size_t)s * H1 + blk * 4 + u1], f16_bits(h));
            }
        }

        // ---- pre2[s-1] = this block's 32 wih2 rows · h1[s-1] (intra-wave handoff) ----
        float pb[8];
        if (s >= 1) {
            float pv[8];
            #pragma unroll
            for (int d = 0; d < 8; ++d) pv[d] = 0.f;
            #pragma unroll
            for (int d = 0; d < 8; ++d) {
                int r = wv * 8 + d;
                uint4 w0 = *(const uint4*)&wih2_w[r * 512 + ln1 * 4];
                uint4 w1 = *(const uint4*)&wih2_w[r * 512 + ln1 * 4 + 256];
                DOT4(pv[d], w0, hA);
                DOT4(pv[d], w1, hB);
            }
            #pragma unroll
            for (int d = 0; d < 8; ++d) pb[d] = bcast_lane63(red64(pv[d]));
        }

        // ---- Phase B': poll h2[s-2] (two 64-bit loads = 8 f16), stage direct ----
        if (s >= 2) {
            const uint64_t* s2 = (const uint64_t*)(comm2 + (size_t)(s - 2) * H2);
            uint64_t qa, qb;
            for (;;) {
                qa = ald64(&s2[tid]);
                qb = ald64(&s2[tid + 256]);
                if (!(bad16x4(qa) | bad16x4(qb))) break;
                __builtin_amdgcn_s_sleep(1);
            }
            uint32_t* d = h2b + (s & 1) * 1024;
            union { uint64_t q; uint2 w; } x;
            x.q = qa; *(uint2*)&d[2 * tid] = x.w;              // words 2tid,2tid+1
            x.q = qb; *(uint2*)&d[512 + 2 * tid] = x.w;        // words 512+2tid,+1
        }
        __syncthreads();   // the single barrier per step (protects h2b)

        // ---- Phase C: h2[s-1] ----
        if (s >= 1) {
            float b0 = 0.f, b1 = 0.f, b2 = 0.f, b3 = 0.f;
            if (s >= 2) {
                const uint32_t* h2p = h2b + (s & 1) * 1024;
                #pragma unroll
                for (int j = 0; j < 8; ++j) {
                    uint4 hx = *(const uint4*)&h2p[ln2 * 4 + j * 128];
                    uint4 w0 = *(const uint4*)&whh2_w[u2l * 1024 + ln2 * 4 + j * 128];
                    DOT4(b0, w0, hx);
                    DOT4(b1, wreg[j], hx);
                    DOT4(b2, wreg[8 + j], hx);
                    DOT4(b3, wreg[16 + j], hx);
                }
            }
            b0 = red32(b0); b1 = red32(b1); b2 = red32(b2); b3 = red32(b3);
            if (ln2 == 31) {   // per-32 totals live on wave lanes 31 and 63
                int half = u2l & 1;
                float iv = fsig(pb[half * 4 + 0] + b2g[0] + b0);
                float fv = fsig(pb[half * 4 + 1] + b2g[1] + b1);
                float gv = ftanh(pb[half * 4 + 2] + b2g[2] + b2);
                float ov = fsig(pb[half * 4 + 3] + b2g[3] + b3);
                c2 = fv * c2 + iv * gv;
                float h = ov * ftanh(c2);
                ast16(&comm2[(size_t)(s - 1) * H2 + blk * 8 + u2l], f16_bits(h));
            }
        }

        #pragma unroll
        for (int g = 0; g < 4; ++g) pc[g] = pn[g];
    }
}

// ---------------- small matvec (f16 input vector) ----------------
__global__ __launch_bounds__(256) void linear_vec_f16_kernel(const float* __restrict__ W,
                                                             const float* __restrict__ bias,
                                                             const ushort_t* __restrict__ x,
                                                             float* __restrict__ out,
                                                             int N, int K) {
    int wave = threadIdx.x >> 6;
    int lane = threadIdx.x & 63;
    int j = blockIdx.x * 4 + wave;
    if (j >= N) return;
    const float* wr = W + (size_t)j * K;
    float s = 0.0f;
    for (int k = lane; k < K; k += 64) s += wr[k] * f16_val(x[k]);
    #pragma unroll
    for (int off = 32; off > 0; off >>= 1) s += __shfl_down(s, off, 64);
    if (lane == 0) out[j] = s + bias[j];
}

// ---------------- small matvec (f32 input vector) ----------------
__global__ __launch_bounds__(256) void linear_vec_kernel(const float* __restrict__ W,
                                                         const float* __restrict__ bias,
                                                         const float* __restrict__ x,
                                                         float* __restrict__ out,
                                                         int N, int K) {
    int wave = threadIdx.x >> 6;
    int lane = threadIdx.x & 63;
    int j = blockIdx.x * 4 + wave;
    if (j >= N) return;
    const float* wr = W + (size_t)j * K;
    float s = 0.0f;
    for (int k = lane; k < K; k += 64) s += wr[k] * x[k];
    #pragma unroll
    for (int off = 32; off > 0; off >>= 1) s += __shfl_down(s, off, 64);
    if (lane == 0) out[j] = s + bias[j];
}

extern "C" void kernel_launch(void* const* d_in, const int* in_sizes, int n_in,
                              void* d_out, int out_size, void* d_ws, size_t ws_size,
                              hipStream_t stream) {
    const float* x_f    = (const float*)d_in[0];
    const float* wih1_f = (const float*)d_in[1];
    const float* whh1_f = (const float*)d_in[2];
    const float* bih1   = (const float*)d_in[3];
    const float* bhh1   = (const float*)d_in[4];
    const float* wih2_f = (const float*)d_in[5];
    const float* whh2_f = (const float*)d_in[6];
    const float* bih2   = (const float*)d_in[7];
    const float* bhh2   = (const float*)d_in[8];
    const float* wl1    = (const float*)d_in[9];
    const float* bl1    = (const float*)d_in[10];
    const float* wl2    = (const float*)d_in[11];
    const float* bl2    = (const float*)d_in[12];

    uint8_t* base = (uint8_t*)d_ws;
    size_t off = 0;
    auto alloc = [&](size_t bytes) { size_t o = off; off = (off + bytes + 255) & ~(size_t)255; return o; };

    size_t pre1_off  = alloc((size_t)T_SEQ * G1 * 2);   // f16 [T,4096]
    size_t comm1_off = alloc((size_t)T_SEQ * H1 * 2);   // f16 [T,1024]
    size_t comm2_off = alloc((size_t)T_SEQ * H2 * 2);   // f16 [T,2048]
    size_t whh1_off  = alloc((size_t)G1 * H1 * 2);
    size_t whh2_off  = alloc((size_t)G2 * H2 * 2);
    size_t wih1_off  = alloc((size_t)G1 * IN_SZ * 2);
    size_t wih2_off  = alloc((size_t)G2 * H1 * 2);
    size_t xb_off    = alloc((size_t)T_SEQ * IN_SZ * 2);
    size_t p1_off    = alloc((size_t)L1OUT * 4);

    f16_t*    pre1  = (f16_t*)(base + pre1_off);
    ushort_t* comm1 = (ushort_t*)(base + comm1_off);
    ushort_t* comm2 = (ushort_t*)(base + comm2_off);
    ushort_t* whh1h = (ushort_t*)(base + whh1_off);
    ushort_t* whh2h = (ushort_t*)(base + whh2_off);
    f16_t*    wih1h = (f16_t*)(base + wih1_off);
    ushort_t* wih2h = (ushort_t*)(base + wih2_off);
    f16_t*    xb    = (f16_t*)(base + xb_off);
    float*    p1    = (float*)(base + p1_off);

    // poison sentinel comm buffers: byte 0x7C -> every f16 = 0x7C7C (NaN pattern)
    (void)hipMemsetAsync(comm1, 0x7C, (size_t)T_SEQ * H1 * 2, stream);
    (void)hipMemsetAsync(comm2, 0x7C, (size_t)T_SEQ * H2 * 2, stream);

    // f32 -> f16 conversions
    cvt_f16_kernel<<<2048, 256, 0, stream>>>(x_f,    xb,            T_SEQ * IN_SZ);
    cvt_f16_kernel<<<2048, 256, 0, stream>>>(wih1_f, wih1h,         G1 * IN_SZ);
    cvt_f16_kernel<<<2048, 256, 0, stream>>>(whh1_f, (f16_t*)whh1h, G1 * H1);
    cvt_f16_kernel<<<2048, 256, 0, stream>>>(wih2_f, (f16_t*)wih2h, G2 * H1);
    cvt_f16_kernel<<<4096, 256, 0, stream>>>(whh2_f, (f16_t*)whh2h, G2 * H2);

    // pre1 = x @ wih1^T + (bih1 + bhh1)   [f16 out]
    {
        dim3 grid(G1 / 64, T_SEQ / 64);
        gemm_bt_kernel<<<grid, 256, 0, stream>>>(xb, wih1h, pre1, bih1, bhh1,
                                                 T_SEQ, G1, IN_SZ);
    }

    // fused 2-layer recurrence: 256 blocks, 136KB dynamic LDS
    {
        size_t shmem = (size_t)(16 * 512 + 32 * 512 + 8 * 1024 + 2 * 1024) * 4;
        fused_lstm_kernel<<<256, 256, shmem, stream>>>(
            pre1, whh1h, wih2h, whh2h, bih2, bhh2, comm1, comm2, T_SEQ);
    }

    // p1 = wl1 . h2[T-1] + bl1 ; out = wl2 . p1 + bl2
    const ushort_t* h2_last = comm2 + (size_t)(T_SEQ - 1) * H2;
    linear_vec_f16_kernel<<<L1OUT / 4, 256, 0, stream>>>(wl1, bl1, h2_last, p1, L1OUT, H2);
    linear_vec_kernel<<<OUT_SZ / 4, 256, 0, stream>>>(wl2, bl2, p1, (float*)d_out, OUT_SZ, L1OUT);

    (void)in_sizes; (void)n_in; (void)out_size; (void)ws_size;
}